// Round 1
// baseline (957.529 us; speedup 1.0000x reference)
//
#include <hip/hip_runtime.h>
#include <math.h>

// Problem constants (match reference)
constexpr int BSZ   = 64;
constexpr int NDIM  = 128;
constexpr int KP1   = 16385;        // K+1
constexpr long NDATA = 1000000;
constexpr float T_INV = 1.0f / 0.07f;

constexpr int SEG   = 64;           // segments per batch row
constexpr int CHUNK = 257;          // SEG*CHUNK = 16448 >= KP1

// ---------------------------------------------------------------------------
// Kernel 1: per-(b,segment) online-softmax partials over gathered rows.
// 256 threads = 16 groups of 16 lanes. Each group processes rows strided by 16.
// Each lane holds 8 floats of x[b] and x_jig[b]; a row's 512B is read by the
// 16-lane group as two float4 loads per lane (fully contiguous 512B).
// ---------------------------------------------------------------------------
__global__ __launch_bounds__(256) void partial_kernel(
    const float* __restrict__ x, const int* __restrict__ y,
    const float* __restrict__ xj, const int* __restrict__ idx,
    const float* __restrict__ mem, float4* __restrict__ part)
{
    const int b    = blockIdx.x >> 6;   // blockIdx = b*SEG + seg
    const int seg  = blockIdx.x & (SEG - 1);
    const int tid  = threadIdx.x;
    const int grp  = tid >> 4;          // 0..15
    const int sub  = tid & 15;          // lane within group

    // preload x fragments (8 floats each stream)
    float xr[8], xjr[8];
    const float4* x4  = (const float4*)(x  + b * NDIM);
    const float4* xj4 = (const float4*)(xj + b * NDIM);
    float4 a0 = x4[sub * 2], a1 = x4[sub * 2 + 1];
    float4 b0 = xj4[sub * 2], b1 = xj4[sub * 2 + 1];
    xr[0]=a0.x; xr[1]=a0.y; xr[2]=a0.z; xr[3]=a0.w;
    xr[4]=a1.x; xr[5]=a1.y; xr[6]=a1.z; xr[7]=a1.w;
    xjr[0]=b0.x; xjr[1]=b0.y; xjr[2]=b0.z; xjr[3]=b0.w;
    xjr[4]=b1.x; xjr[5]=b1.y; xjr[6]=b1.z; xjr[7]=b1.w;

    const int k0   = seg * CHUNK;
    const int kend = min(k0 + CHUNK, KP1);

    float mx = -1e30f, sx = 0.f, mj = -1e30f, sj = 0.f;

    for (int k = k0 + grp; k < kend; k += 16) {
        const int row = (k == 0) ? y[b] : idx[b * KP1 + k];
        const float4* w4 = (const float4*)(mem + (long)row * NDIM);
        float4 wa = w4[sub * 2];
        float4 wb = w4[sub * 2 + 1];
        float dx = wa.x*xr[0] + wa.y*xr[1] + wa.z*xr[2] + wa.w*xr[3]
                 + wb.x*xr[4] + wb.y*xr[5] + wb.z*xr[6] + wb.w*xr[7];
        float dj = wa.x*xjr[0] + wa.y*xjr[1] + wa.z*xjr[2] + wa.w*xjr[3]
                 + wb.x*xjr[4] + wb.y*xjr[5] + wb.z*xjr[6] + wb.w*xjr[7];
        // reduce across the 16-lane group (butterfly; all lanes end with sum)
        #pragma unroll
        for (int off = 8; off; off >>= 1) {
            dx += __shfl_xor(dx, off);
            dj += __shfl_xor(dj, off);
        }
        const float lx = dx * T_INV;
        const float lj = dj * T_INV;
        float nm = fmaxf(mx, lx);
        sx = sx * __expf(mx - nm) + __expf(lx - nm); mx = nm;
        nm = fmaxf(mj, lj);
        sj = sj * __expf(mj - nm) + __expf(lj - nm); mj = nm;
    }

    // combine the 16 groups (state is replicated across a group's lanes)
    __shared__ float4 gdata[16];
    if (sub == 0) gdata[grp] = make_float4(mx, sx, mj, sj);
    __syncthreads();

    if (tid < 16) {
        float4 v = gdata[tid];
        float m1 = v.x, s1 = v.y, m2 = v.z, s2 = v.w;
        #pragma unroll
        for (int off = 8; off; off >>= 1) {
            float om1 = __shfl_xor(m1, off), os1 = __shfl_xor(s1, off);
            float om2 = __shfl_xor(m2, off), os2 = __shfl_xor(s2, off);
            float nm = fmaxf(m1, om1);
            s1 = s1 * __expf(m1 - nm) + os1 * __expf(om1 - nm); m1 = nm;
            nm = fmaxf(m2, om2);
            s2 = s2 * __expf(m2 - nm) + os2 * __expf(om2 - nm); m2 = nm;
        }
        if (tid == 0) part[b * SEG + seg] = make_float4(m1, s1, m2, s2);
    }
}

// ---------------------------------------------------------------------------
// Kernel 2: copy memory -> out+1 (out[0] holds the loss, so stores are
// shifted by one float; use aligned float4 loads + scalar stores).
// ---------------------------------------------------------------------------
__global__ __launch_bounds__(256) void copy_kernel(
    const float* __restrict__ mem, float* __restrict__ out)
{
    const float4* m4 = (const float4*)mem;
    const long n4 = NDATA * NDIM / 4;   // 32M float4
    const long stride = (long)gridDim.x * blockDim.x;
    for (long i = (long)blockIdx.x * blockDim.x + threadIdx.x; i < n4; i += stride) {
        float4 v = m4[i];
        long o = 1 + i * 4;
        out[o]     = v.x;
        out[o + 1] = v.y;
        out[o + 2] = v.z;
        out[o + 3] = v.w;
    }
}

// ---------------------------------------------------------------------------
// Kernel 3: EMA + L2-normalize the 64 positive rows (after the copy).
// ---------------------------------------------------------------------------
__global__ __launch_bounds__(128) void ema_kernel(
    const float* __restrict__ x, const int* __restrict__ y,
    const float* __restrict__ mem, float* __restrict__ out)
{
    const int b = blockIdx.x;
    const int d = threadIdx.x;      // 128 threads
    const int row = y[b];
    const float w = mem[(long)row * NDIM + d] * 0.5f + x[b * NDIM + d] * 0.5f;
    float ss = w * w;
    #pragma unroll
    for (int off = 32; off; off >>= 1) ss += __shfl_xor(ss, off);
    __shared__ float tot[2];
    if ((d & 63) == 0) tot[d >> 6] = ss;
    __syncthreads();
    const float nrm = sqrtf(tot[0] + tot[1]);
    const float denom = fmaxf(nrm, 1e-12f);
    out[1 + (long)row * NDIM + d] = w / denom;
}

// ---------------------------------------------------------------------------
// Kernel 4: final reduce — one wave, lane b merges its 64 partials, computes
// the positive logit, CE, then a wave-sum writes the scalar loss.
// ---------------------------------------------------------------------------
__global__ __launch_bounds__(64) void reduce_kernel(
    const float* __restrict__ x, const int* __restrict__ y,
    const float* __restrict__ xj, const float* __restrict__ mem,
    const float4* __restrict__ part, float* __restrict__ out)
{
    const int b = threadIdx.x;      // 64 lanes
    float mx = -1e30f, sx = 0.f, mj = -1e30f, sj = 0.f;
    for (int s = 0; s < SEG; ++s) {
        float4 v = part[b * SEG + s];
        float nm = fmaxf(mx, v.x);
        sx = sx * __expf(mx - nm) + v.y * __expf(v.x - nm); mx = nm;
        nm = fmaxf(mj, v.z);
        sj = sj * __expf(mj - nm) + v.w * __expf(v.z - nm); mj = nm;
    }
    // positive logit: dot(memory[y[b]], x[b]) and (.., x_jig[b])
    const int row = y[b];
    const float4* w4  = (const float4*)(mem + (long)row * NDIM);
    const float4* x4  = (const float4*)(x  + b * NDIM);
    const float4* xj4 = (const float4*)(xj + b * NDIM);
    float d0 = 0.f, d0j = 0.f;
    #pragma unroll
    for (int i = 0; i < NDIM / 4; ++i) {
        float4 w = w4[i], a = x4[i], aj = xj4[i];
        d0  += w.x*a.x  + w.y*a.y  + w.z*a.z  + w.w*a.w;
        d0j += w.x*aj.x + w.y*aj.y + w.z*aj.z + w.w*aj.w;
    }
    const float l0  = d0  * T_INV;
    const float l0j = d0j * T_INV;
    const float ce  = (mx + logf(sx)) - l0;
    const float cej = (mj + logf(sj)) - l0j;
    float c = 0.5f * (ce + cej) * (1.0f / (float)BSZ);
    #pragma unroll
    for (int off = 32; off; off >>= 1) c += __shfl_xor(c, off);
    if (b == 0) out[0] = c;
}

extern "C" void kernel_launch(void* const* d_in, const int* in_sizes, int n_in,
                              void* d_out, int out_size, void* d_ws, size_t ws_size,
                              hipStream_t stream) {
    const float* x   = (const float*)d_in[0];
    const int*   y   = (const int*)  d_in[1];
    const float* xj  = (const float*)d_in[2];
    const int*   idx = (const int*)  d_in[3];
    const float* mem = (const float*)d_in[4];
    float* out = (float*)d_out;
    float4* part = (float4*)d_ws;   // 64*64*16B = 64 KiB

    // 1) online-softmax partials over the gathered rows (reads OLD memory)
    partial_kernel<<<dim3(BSZ * SEG), dim3(256), 0, stream>>>(x, y, xj, idx, mem, part);
    // 2) bulk copy memory -> new_memory (out+1)
    copy_kernel<<<dim3(4096), dim3(256), 0, stream>>>(mem, out);
    // 3) overwrite the 64 positive rows with EMA-normalized values
    ema_kernel<<<dim3(BSZ), dim3(128), 0, stream>>>(x, y, mem, out);
    // 4) merge partials -> scalar loss in out[0]
    reduce_kernel<<<dim3(1), dim3(64), 0, stream>>>(x, y, xj, mem, part, out);
}